// Round 13
// baseline (183.053 us; speedup 1.0000x reference)
//
#include <hip/hip_runtime.h>
#include <hip/hip_bf16.h>

#define NBH 32          // B*H
#define SEQ 2048
#define DIM 64

typedef __attribute__((ext_vector_type(4))) float f32x4;
typedef __attribute__((ext_vector_type(8))) short bf16x8;

__device__ __forceinline__ unsigned short bfbits(float f) {
    unsigned u = __builtin_bit_cast(unsigned, f);
    u += 0x7FFFu + ((u >> 16) & 1u);          // RTNE
    return (unsigned short)(u >> 16);
}

// async global->LDS DMA, 16B per lane (dest = wave-uniform LDS base + lane*16)
__device__ __forceinline__ void dma16(const float* g, const float* l) {
    __builtin_amdgcn_global_load_lds(
        (const __attribute__((address_space(1))) void*)g,
        (__attribute__((address_space(3))) void*)(unsigned)(uintptr_t)l,
        16, 0, 0);
}

// ---------------------------------------------------------------------------
// V prep (unchanged layout): ws[bh][tau][ks][dt][lane][j] = bf16 of
//   V[bh][tau*64 + ks*32 + (lane>>4)*8 + j][dt*16 + (lane&15)]
// => B-frag for k-slice K32 (0..63), slice dt at offset K32*2048 + dt*512.
// ---------------------------------------------------------------------------
__global__ __launch_bounds__(256)
void vprep_kernel(const float* __restrict__ v, unsigned short* __restrict__ wsv)
{
    const int blk = blockIdx.x;            // bh*32 + tau
    const int bh  = blk >> 5, tau = blk & 31;
    const float* vp = v + ((size_t)bh * SEQ + tau * 64) * DIM;
    unsigned short* op = wsv + (size_t)blk * 4096;

    for (int fl = threadIdx.x; fl < 512; fl += 256) {
        const int ks = fl >> 8, dt = (fl >> 6) & 3, lane = fl & 63;
        const int g = lane >> 4, c = lane & 15;
        const float* sp = vp + (ks * 32 + g * 8) * DIM + dt * 16 + c;
        bf16x8 frag;
#pragma unroll
        for (int j = 0; j < 8; ++j)
            frag[j] = (short)bfbits(sp[j * DIM]);
        *reinterpret_cast<bf16x8*>(op + fl * 8) = frag;
    }
}

// ---------------------------------------------------------------------------
// Main kernel: persistent 1 block/CU. S staged by deep async global_load_lds
// into double-buffered LDS [16 rows][1024 k] fp32. Counted vmcnt(8) keeps the
// next buffer's DMA in flight across barriers. Swizzle: LDS[r][granule x]
// holds global granule x^(r&7) (source-pre-swizzled; linear DMA dest); reads
// XOR the same key -> balanced banks. Wave w = (dt = w&3, ksub = w>>2):
// exp+pack A-frag in registers, MFMA vs prepped V B-frags; ones-column MFMA
// accumulates the softmax denominator. k-half reduce via LDS per strip.
// ---------------------------------------------------------------------------
__global__ __launch_bounds__(512, 1)
void softmaxv_kernel(const float* __restrict__ scores,
                     const unsigned short* __restrict__ vfrags,
                     float* __restrict__ out)
{
    __shared__ float stage[2][16][1024];   // 128 KB
    __shared__ float red[4][64][8];        // 8 KB (k-half reduce)

    const int tid  = threadIdx.x;
    const int w    = tid >> 6;        // 0..7
    const int lane = tid & 63;
    const int dt   = w & 3;           // output col slice
    const int ksub = w >> 2;          // k half within buffer
    const int g    = lane >> 4;       // 0..3
    const int c    = lane & 15;       // 0..15

    const int bid = blockIdx.x;
    const int bh  = bid & 31;         // same-bh blocks share an XCD (bid%8)
    const int s   = bid >> 5;         // q-range [s*256, s*256+256)

    const float* sblk = scores + ((size_t)bh * SEQ + s * 256) * SEQ;
    const unsigned short* vb = vfrags + (size_t)bh * 32 * 4096 + lane * 8;
    float* const oblk = out + ((size_t)bh * SEQ + s * 256) * DIM;

    bf16x8 ones;
#pragma unroll
    for (int j = 0; j < 8; ++j) ones[j] = (short)0x3F80;   // bf16 1.0

    // issue the 8 DMA instructions this wave owns for buffer n (rows 2w,2w+1)
#define ISSUE(n)                                                               \
    {                                                                          \
        const int strip_ = (n) >> 1, half_ = (n) & 1, p_ = (n) & 1;            \
        _Pragma("unroll")                                                      \
        for (int rr = 0; rr < 2; ++rr) {                                       \
            const int r   = 2 * w + rr;                                        \
            const int key = r & 7;                                             \
            const float* srow = sblk + (size_t)(strip_ * 16 + r) * SEQ +       \
                                half_ * 1024 + ((lane ^ key) << 2);            \
            const float* lrow = &stage[p_][r][0];                              \
            _Pragma("unroll")                                                  \
            for (int seg = 0; seg < 4; ++seg)                                  \
                dma16(srow + seg * 256, lrow + seg * 256);                     \
        }                                                                      \
    }

    ISSUE(0)
    ISSUE(1)

    f32x4 acc  = (f32x4)0.0f;
    f32x4 accl = (f32x4)0.0f;

    for (int n = 0; n < 32; ++n) {
        const int strip = n >> 1, half = n & 1, p = n & 1;
        if (!half) { acc = (f32x4)0.0f; accl = (f32x4)0.0f; }

        // DMA(n) complete: >=8 younger ops (DMA(n+1)) outstanding => counted
        // wait never drains the prefetch. Last phase: full drain.
        if (n < 31) asm volatile("s_waitcnt vmcnt(8)" ::: "memory");
        else        asm volatile("s_waitcnt vmcnt(0)" ::: "memory");
        __builtin_amdgcn_s_barrier();

        // ---- consume buffer p: 16 k-steps of 32 for this wave's ksub ----
        const float* sb = &stage[p][0][0];
#pragma unroll
        for (int kk = 0; kk < 16; ++kk) {
            const int ks = ksub * 16 + kk;
            const int g0 = ks * 8 + g * 2;                 // granule index
            const f32x4 a = *reinterpret_cast<const f32x4*>(
                sb + c * 1024 + ((g0 ^ (c & 7)) << 2));
            const f32x4 b = *reinterpret_cast<const f32x4*>(
                sb + c * 1024 + (((g0 + 1) ^ (c & 7)) << 2));
            const float e0 = __expf(a[0]), e1 = __expf(a[1]);
            const float e2 = __expf(a[2]), e3 = __expf(a[3]);
            const float e4 = __expf(b[0]), e5 = __expf(b[1]);
            const float e6 = __expf(b[2]), e7 = __expf(b[3]);
            bf16x8 pa;
            pa[0] = (short)bfbits(e0); pa[1] = (short)bfbits(e1);
            pa[2] = (short)bfbits(e2); pa[3] = (short)bfbits(e3);
            pa[4] = (short)bfbits(e4); pa[5] = (short)bfbits(e5);
            pa[6] = (short)bfbits(e6); pa[7] = (short)bfbits(e7);

            const int K32 = half * 32 + ks;                // global k-slice
            const bf16x8 vf = *reinterpret_cast<const bf16x8*>(
                vb + (size_t)K32 * 2048 + dt * 512);

            acc  = __builtin_amdgcn_mfma_f32_16x16x32_bf16(pa, vf,   acc,  0, 0, 0);
            accl = __builtin_amdgcn_mfma_f32_16x16x32_bf16(pa, ones, accl, 0, 0, 0);
        }

        // ---- strip end: ksub=1 publishes partials ----
        if (half && ksub == 1) {
            *reinterpret_cast<f32x4*>(&red[dt][lane][0]) = acc;
            *reinterpret_cast<f32x4*>(&red[dt][lane][4]) = accl;
        }

        // all LDS reads (stage + red writes) done before buffer p is re-DMA'd
        asm volatile("s_waitcnt lgkmcnt(0)\n\ts_barrier" ::: "memory");

        if (half && ksub == 0) {
            const f32x4 a2 = *reinterpret_cast<const f32x4*>(&red[dt][lane][0]);
            const f32x4 l2 = *reinterpret_cast<const f32x4*>(&red[dt][lane][4]);
            const f32x4 at = acc + a2;
            const f32x4 lt = accl + l2;
            float* op = oblk + (size_t)(strip * 16) * DIM + dt * 16 + c;
#pragma unroll
            for (int r = 0; r < 4; ++r)
                op[(size_t)(g * 4 + r) * DIM] = at[r] * (1.0f / lt[r]);
        }

        if (n + 2 < 32) ISSUE(n + 2)
    }
#undef ISSUE
}

extern "C" void kernel_launch(void* const* d_in, const int* in_sizes, int n_in,
                              void* d_out, int out_size, void* d_ws, size_t ws_size,
                              hipStream_t stream)
{
    const float* scores = (const float*)d_in[0];
    const float* v      = (const float*)d_in[1];
    float* out          = (float*)d_out;
    unsigned short* wsv = (unsigned short*)d_ws;   // 8 MB of ws used

    vprep_kernel<<<dim3(NBH * 32), dim3(256), 0, stream>>>(v, wsv);
    softmaxv_kernel<<<dim3(256), dim3(512), 0, stream>>>(scores, wsv, out);
}

// Round 14
// 114.562 us; speedup vs baseline: 1.5979x; 1.5979x over previous
//
#include <hip/hip_runtime.h>
#include <hip/hip_bf16.h>

#define NBH  32          // B*H
#define SEQ  2048
#define DIM  64
#define PSTR 2056        // ushorts per P row (pad +8 -> 2-way A-frag reads, free)

typedef __attribute__((ext_vector_type(4))) float f32x4;
typedef __attribute__((ext_vector_type(8))) short bf16x8;

__device__ __forceinline__ unsigned short bfbits(float f) {
    unsigned u = __builtin_bit_cast(unsigned, f);
    u += 0x7FFFu + ((u >> 16) & 1u);          // RTNE
    return (unsigned short)(u >> 16);
}
__device__ __forceinline__ unsigned pk(float a, float b) {
    return (unsigned)bfbits(a) | ((unsigned)bfbits(b) << 16);
}

// ---------------------------------------------------------------------------
// V prep (unchanged layout): ws[bh][tau][ks][dt][lane][j] = bf16 of
//   V[bh][tau*64 + ks*32 + (lane>>4)*8 + j][dt*16 + (lane&15)]
// => B-frag for global k-slice K32 (0..63), dt at ushort offset K32*2048+dt*512.
// ---------------------------------------------------------------------------
__global__ __launch_bounds__(256)
void vprep_kernel(const float* __restrict__ v, unsigned short* __restrict__ wsv)
{
    const int blk = blockIdx.x;            // bh*32 + tau
    const int bh  = blk >> 5, tau = blk & 31;
    const float* vp = v + ((size_t)bh * SEQ + tau * 64) * DIM;
    unsigned short* op = wsv + (size_t)blk * 4096;

    for (int fl = threadIdx.x; fl < 512; fl += 256) {
        const int ks = fl >> 8, dt = (fl >> 6) & 3, lane = fl & 63;
        const int g = lane >> 4, c = lane & 15;
        const float* sp = vp + (ks * 32 + g * 8) * DIM + dt * 16 + c;
        bf16x8 frag;
#pragma unroll
        for (int j = 0; j < 8; ++j)
            frag[j] = (short)bfbits(sp[j * DIM]);
        *reinterpret_cast<bf16x8*>(op + fl * 8) = frag;
    }
}

// ---------------------------------------------------------------------------
// Main kernel: persistent 1 block/CU, 512 threads. Per phase the block
// consumes a CONTIGUOUS 128KB S-window (16 adjacent rows); wave w owns rows
// {2w, 2w+1}, each read as 8 dense 1KB instructions (lane L -> L*16B, probe-B
// geometry). All 16 loads issued back-to-back; next window issued before the
// lgkm-only barrier -> in flight across the whole MFMA phase. exp+pack ->
// P-LDS [16][PSTR] (transpose); V-fragments REGISTER-resident (preloaded
// once, wave=(dt,ksub)); ones-column MFMA forms the denominator; k-half
// reduce via small LDS. Two lgkm-only barriers per phase, zero vmcnt drains.
// ---------------------------------------------------------------------------
__global__ __launch_bounds__(512, 2)
void softmaxv_kernel(const float* __restrict__ scores,
                     const unsigned short* __restrict__ vfrags,
                     float* __restrict__ out)
{
    __shared__ unsigned short P[16 * PSTR];   // 65,792 B
    __shared__ float red[4][64][8];           // 8,192 B

    const int tid  = threadIdx.x;
    const int w    = tid >> 6;        // 0..7
    const int lane = tid & 63;
    const int dt   = w & 3;           // output col slice
    const int ksub = w >> 2;          // k half (0: k<1024, 1: k>=1024)
    const int g    = lane >> 4;       // 0..3
    const int c    = lane & 15;       // 0..15

    const int bid = blockIdx.x;
    const int bh  = bid & 31;         // same-bh blocks share an XCD (bid%8)
    const int s   = bid >> 5;         // q-range [s*256, s*256+256)

    const float* sblk = scores + ((size_t)bh * SEQ + s * 256) * SEQ;
    const unsigned short* vb = vfrags + (size_t)bh * 32 * 4096 + lane * 8;
    float* const oblk = out + ((size_t)bh * SEQ + s * 256) * DIM;

    bf16x8 ones;
#pragma unroll
    for (int j = 0; j < 8; ++j) ones[j] = (short)0x3F80;   // bf16 1.0

    // ---- V fragments register-resident: 32 slices for this (ksub, dt) ----
    bf16x8 vreg[32];
#pragma unroll
    for (int kk = 0; kk < 32; ++kk)
        vreg[kk] = *reinterpret_cast<const bf16x8*>(
            vb + (size_t)(ksub * 32 + kk) * 2048 + dt * 512);

    const int r0 = 2 * w;             // this wave's two rows within a tile
    f32x4 st[2][8];                   // staged S: 2 rows x 8 dense 1KB segs

#define ISSUE(t)                                                               \
    {                                                                          \
        _Pragma("unroll")                                                      \
        for (int rr = 0; rr < 2; ++rr)                                         \
            _Pragma("unroll")                                                  \
            for (int j = 0; j < 8; ++j)                                        \
                st[rr][j] = *reinterpret_cast<const f32x4*>(                   \
                    sblk + (size_t)((t) * 16 + r0 + rr) * SEQ +                \
                    j * 256 + (lane << 2));                                    \
    }

#define LDS_BAR asm volatile("s_waitcnt lgkmcnt(0)\n\ts_barrier" ::: "memory");

    ISSUE(0)

    for (int t = 0; t < 16; ++t) {
        // ---- pack: consume staged rows, exp, write P (transpose) ----
#pragma unroll
        for (int rr = 0; rr < 2; ++rr) {
            const int row = r0 + rr;
#pragma unroll
            for (int j = 0; j < 8; ++j) {
                const f32x4 sv = st[rr][j];
                const float e0 = __expf(sv[0]), e1 = __expf(sv[1]);
                const float e2 = __expf(sv[2]), e3 = __expf(sv[3]);
                uint2 pw = make_uint2(pk(e0, e1), pk(e2, e3));
                *reinterpret_cast<uint2*>(&P[row * PSTR + j * 256 + lane * 4]) = pw;
            }
        }
        if (t < 15) ISSUE(t + 1)      // next window rides through barrier+MFMA

        LDS_BAR   // P visible; S loads stay in flight (lgkm-only)

        // ---- MFMA: 32 k-slices for this (ksub, dt) ----
        f32x4 acc  = (f32x4)0.0f;
        f32x4 accl = (f32x4)0.0f;
#pragma unroll
        for (int kk = 0; kk < 32; ++kk) {
            const int K = ksub * 32 + kk;
            const bf16x8 a = *reinterpret_cast<const bf16x8*>(
                &P[c * PSTR + K * 32 + g * 8]);
            acc  = __builtin_amdgcn_mfma_f32_16x16x32_bf16(a, vreg[kk], acc,  0, 0, 0);
            accl = __builtin_amdgcn_mfma_f32_16x16x32_bf16(a, ones,     accl, 0, 0, 0);
        }

        if (ksub == 1) {
            *reinterpret_cast<f32x4*>(&red[dt][lane][0]) = acc;
            *reinterpret_cast<f32x4*>(&red[dt][lane][4]) = accl;
        }

        LDS_BAR   // red visible AND all P reads done before next pack

        if (ksub == 0) {
            const f32x4 a2 = *reinterpret_cast<const f32x4*>(&red[dt][lane][0]);
            const f32x4 l2 = *reinterpret_cast<const f32x4*>(&red[dt][lane][4]);
            const f32x4 at = acc + a2;
            const f32x4 lt = accl + l2;
            float* op = oblk + (size_t)(t * 16) * DIM + dt * 16 + c;
#pragma unroll
            for (int r = 0; r < 4; ++r)
                op[(size_t)(g * 4 + r) * DIM] = at[r] * (1.0f / lt[r]);
        }
    }
#undef ISSUE
#undef LDS_BAR
}

extern "C" void kernel_launch(void* const* d_in, const int* in_sizes, int n_in,
                              void* d_out, int out_size, void* d_ws, size_t ws_size,
                              hipStream_t stream)
{
    const float* scores = (const float*)d_in[0];
    const float* v      = (const float*)d_in[1];
    float* out          = (float*)d_out;
    unsigned short* wsv = (unsigned short*)d_ws;   // 8 MB of ws used

    vprep_kernel<<<dim3(NBH * 32), dim3(256), 0, stream>>>(v, wsv);
    softmaxv_kernel<<<dim3(256), dim3(512), 0, stream>>>(scores, wsv, out);
}

// Round 15
// 113.613 us; speedup vs baseline: 1.6112x; 1.0083x over previous
//
#include <hip/hip_runtime.h>
#include <hip/hip_bf16.h>

#define NBH  32          // B*H
#define SEQ  2048
#define DIM  64
#define PSTR 2056        // ushorts per P row (pad +8 -> 2-way A-frag reads, free)

typedef __attribute__((ext_vector_type(4))) float f32x4;
typedef __attribute__((ext_vector_type(8))) short bf16x8;

__device__ __forceinline__ unsigned short bfbits(float f) {
    unsigned u = __builtin_bit_cast(unsigned, f);
    u += 0x7FFFu + ((u >> 16) & 1u);          // RTNE
    return (unsigned short)(u >> 16);
}
__device__ __forceinline__ unsigned pk(float a, float b) {
    return (unsigned)bfbits(a) | ((unsigned)bfbits(b) << 16);
}

// ---------------------------------------------------------------------------
// V prep (unchanged layout): ws[bh][tau][ks][dt][lane][j] = bf16 of
//   V[bh][tau*64 + ks*32 + (lane>>4)*8 + j][dt*16 + (lane&15)]
// => B-frag for global k-slice K32 (0..63), dt at ushort offset K32*2048+dt*512.
// ---------------------------------------------------------------------------
__global__ __launch_bounds__(256)
void vprep_kernel(const float* __restrict__ v, unsigned short* __restrict__ wsv)
{
    const int blk = blockIdx.x;            // bh*32 + tau
    const int bh  = blk >> 5, tau = blk & 31;
    const float* vp = v + ((size_t)bh * SEQ + tau * 64) * DIM;
    unsigned short* op = wsv + (size_t)blk * 4096;

    for (int fl = threadIdx.x; fl < 512; fl += 256) {
        const int ks = fl >> 8, dt = (fl >> 6) & 3, lane = fl & 63;
        const int g = lane >> 4, c = lane & 15;
        const float* sp = vp + (ks * 32 + g * 8) * DIM + dt * 16 + c;
        bf16x8 frag;
#pragma unroll
        for (int j = 0; j < 8; ++j)
            frag[j] = (short)bfbits(sp[j * DIM]);
        *reinterpret_cast<bf16x8*>(op + fl * 8) = frag;
    }
}

// ---------------------------------------------------------------------------
// Main kernel (r14 structure + per-segment interleaved reissue):
// persistent 1 block/CU, 512 threads. Per phase the block consumes a
// CONTIGUOUS 128KB S-window (16 adjacent rows); wave w owns rows {2w, 2w+1},
// each read as 8 dense 1KB instructions (lane L -> L*16B). NEW: each segment's
// replacement load for window t+1 is issued IMMEDIATELY after that segment is
// consumed, inside the pack loop -> the CU memory queue never drains at phase
// boundaries. exp+pack -> P-LDS (transpose); V register-resident
// (wave=(dt,ksub)); ones-column MFMA denominator; k-half reduce via LDS.
// Two lgkm-only barriers per phase, zero vmcnt drains.
// ---------------------------------------------------------------------------
__global__ __launch_bounds__(512, 2)
void softmaxv_kernel(const float* __restrict__ scores,
                     const unsigned short* __restrict__ vfrags,
                     float* __restrict__ out)
{
    __shared__ unsigned short P[16 * PSTR];   // 65,792 B
    __shared__ float red[4][64][8];           // 8,192 B

    const int tid  = threadIdx.x;
    const int w    = tid >> 6;        // 0..7
    const int lane = tid & 63;
    const int dt   = w & 3;           // output col slice
    const int ksub = w >> 2;          // k half (0: k<1024, 1: k>=1024)
    const int g    = lane >> 4;       // 0..3
    const int c    = lane & 15;       // 0..15

    const int bid = blockIdx.x;
    const int bh  = bid & 31;         // same-bh blocks share an XCD (bid%8)
    const int s   = bid >> 5;         // q-range [s*256, s*256+256)

    const float* sblk = scores + ((size_t)bh * SEQ + s * 256) * SEQ;
    const unsigned short* vb = vfrags + (size_t)bh * 32 * 4096 + lane * 8;
    float* const oblk = out + ((size_t)bh * SEQ + s * 256) * DIM;

    bf16x8 ones;
#pragma unroll
    for (int j = 0; j < 8; ++j) ones[j] = (short)0x3F80;   // bf16 1.0

    // ---- V fragments register-resident: 32 slices for this (ksub, dt) ----
    bf16x8 vreg[32];
#pragma unroll
    for (int kk = 0; kk < 32; ++kk)
        vreg[kk] = *reinterpret_cast<const bf16x8*>(
            vb + (size_t)(ksub * 32 + kk) * 2048 + dt * 512);

    const int r0 = 2 * w;             // this wave's two rows within a tile
    f32x4 st[2][8];                   // staged S: 2 rows x 8 dense 1KB segs

#define SEG(t, rr, j)                                                          \
    (*reinterpret_cast<const f32x4*>(                                          \
        sblk + (size_t)((t) * 16 + r0 + (rr)) * SEQ + (j) * 256 + (lane << 2)))

#define LDS_BAR asm volatile("s_waitcnt lgkmcnt(0)\n\ts_barrier" ::: "memory");

    // prime window 0
#pragma unroll
    for (int j = 0; j < 8; ++j) { st[0][j] = SEG(0, 0, j); st[1][j] = SEG(0, 1, j); }

    for (int t = 0; t < 16; ++t) {
        // ---- pack: per segment, consume -> reissue for t+1 -> exp+pack ----
#pragma unroll
        for (int j = 0; j < 8; ++j) {
            const f32x4 sv0 = st[0][j];
            const f32x4 sv1 = st[1][j];
            if (t < 15) {                       // reissue this segment early
                st[0][j] = SEG(t + 1, 0, j);
                st[1][j] = SEG(t + 1, 1, j);
            }
            const float a0 = __expf(sv0[0]), a1 = __expf(sv0[1]);
            const float a2 = __expf(sv0[2]), a3 = __expf(sv0[3]);
            const float b0 = __expf(sv1[0]), b1 = __expf(sv1[1]);
            const float b2 = __expf(sv1[2]), b3 = __expf(sv1[3]);
            *reinterpret_cast<uint2*>(&P[r0 * PSTR + j * 256 + lane * 4]) =
                make_uint2(pk(a0, a1), pk(a2, a3));
            *reinterpret_cast<uint2*>(&P[(r0 + 1) * PSTR + j * 256 + lane * 4]) =
                make_uint2(pk(b0, b1), pk(b2, b3));
        }

        LDS_BAR   // P visible; S loads for t+1 stay in flight (lgkm-only)

        // ---- MFMA: 32 k-slices for this (ksub, dt) ----
        f32x4 acc  = (f32x4)0.0f;
        f32x4 accl = (f32x4)0.0f;
#pragma unroll
        for (int kk = 0; kk < 32; ++kk) {
            const int K = ksub * 32 + kk;
            const bf16x8 a = *reinterpret_cast<const bf16x8*>(
                &P[c * PSTR + K * 32 + g * 8]);
            acc  = __builtin_amdgcn_mfma_f32_16x16x32_bf16(a, vreg[kk], acc,  0, 0, 0);
            accl = __builtin_amdgcn_mfma_f32_16x16x32_bf16(a, ones,     accl, 0, 0, 0);
        }

        if (ksub == 1) {
            *reinterpret_cast<f32x4*>(&red[dt][lane][0]) = acc;
            *reinterpret_cast<f32x4*>(&red[dt][lane][4]) = accl;
        }

        LDS_BAR   // red visible AND all P reads done before next pack

        if (ksub == 0) {
            const f32x4 a2 = *reinterpret_cast<const f32x4*>(&red[dt][lane][0]);
            const f32x4 l2 = *reinterpret_cast<const f32x4*>(&red[dt][lane][4]);
            const f32x4 at = acc + a2;
            const f32x4 lt = accl + l2;
            float* op = oblk + (size_t)(t * 16) * DIM + dt * 16 + c;
#pragma unroll
            for (int r = 0; r < 4; ++r)
                op[(size_t)(g * 4 + r) * DIM] = at[r] * (1.0f / lt[r]);
        }
    }
#undef SEG
#undef LDS_BAR
}

extern "C" void kernel_launch(void* const* d_in, const int* in_sizes, int n_in,
                              void* d_out, int out_size, void* d_ws, size_t ws_size,
                              hipStream_t stream)
{
    const float* scores = (const float*)d_in[0];
    const float* v      = (const float*)d_in[1];
    float* out          = (float*)d_out;
    unsigned short* wsv = (unsigned short*)d_ws;   // 8 MB of ws used

    vprep_kernel<<<dim3(NBH * 32), dim3(256), 0, stream>>>(v, wsv);
    softmaxv_kernel<<<dim3(256), dim3(512), 0, stream>>>(scores, wsv, out);
}